// Round 5
// baseline (1064.534 us; speedup 1.0000x reference)
//
#include <hip/hip_runtime.h>
#include <cstdint>
#include <cmath>

// Binarized MLP via i8 MFMA: 16384x1024 -> 2048 -> 2048 -> 2048 -> 2.
// Acts/weights are exactly {-1,+1} as i8; mfma_i32_16x16x64_i8 gives exact
// i32 accumulation. BN+binq folds to per-neuron float threshold.
// R5: 256x128 block tile, BK=64, DOUBLE-buffered LDS (2x24KB=48KB ->
// 3 blocks/CU via __launch_bounds__(512,6)), XCD-aware block swizzle,
// fused prep kernel, final 2-neuron layer fused into layer-3 epilogue.

typedef int i32x4 __attribute__((ext_vector_type(4)));

static constexpr int Bsz = 16384;
static constexpr int Din = 1024;
static constexpr int Hid = 2048;

__device__ __forceinline__ void ld16(const void* g, void* l) {
  __builtin_amdgcn_global_load_lds(
      (const __attribute__((address_space(1))) void*)g,
      (__attribute__((address_space(3))) void*)l, 16, 0, 0);
}

// ---------------- fused prep: all sign-quantizations + BN folds ------------
__global__ void prep_kernel(
    const float* __restrict__ x, const float* __restrict__ w1,
    const float* __restrict__ w2, const float* __restrict__ w3,
    const float* __restrict__ g1, const float* __restrict__ b1,
    const float* __restrict__ m1, const float* __restrict__ v1,
    const float* __restrict__ g2, const float* __restrict__ b2,
    const float* __restrict__ m2, const float* __restrict__ v2,
    const float* __restrict__ g3, const float* __restrict__ b3,
    const float* __restrict__ m3, const float* __restrict__ v3,
    char* __restrict__ A0, char* __restrict__ W1s,
    char* __restrict__ W2s, char* __restrict__ W3s,
    float* __restrict__ a1, float* __restrict__ be1,
    float* __restrict__ a2, float* __restrict__ be2,
    float* __restrict__ a3, float* __restrict__ be3) {
  constexpr int BX = 16384, BW1 = 2048, BW2 = 4096, BW3 = 4096;
  const int blk = blockIdx.x;
  if (blk < BX + BW1 + BW2 + BW3) {
    const float* s;
    char* d;
    float thr = 0.0f;
    int rb;
    if (blk < BX) {
      s = x; d = A0; thr = 0.5f; rb = 0;
    } else if (blk < BX + BW1) {
      s = w1; d = W1s; rb = BX;
    } else if (blk < BX + BW1 + BW2) {
      s = w2; d = W2s; rb = BX + BW1;
    } else {
      s = w3; d = W3s; rb = BX + BW1 + BW2;
    }
    int i = (blk - rb) * 256 + threadIdx.x;
    float4 v = ((const float4*)s)[i];
    char4 o;
    o.x = (v.x >= thr) ? 1 : -1;
    o.y = (v.y >= thr) ? 1 : -1;
    o.z = (v.z >= thr) ? 1 : -1;
    o.w = (v.w >= thr) ? 1 : -1;
    ((char4*)d)[i] = o;
  } else {
    int t = (blk - (BX + BW1 + BW2 + BW3)) * 256 + threadIdx.x;  // 0..6143
    int l = t >> 11, e = t & 2047;
    const float *g, *b, *m, *v;
    float *al, *be;
    if (l == 0) { g = g1; b = b1; m = m1; v = v1; al = a1; be = be1; }
    else if (l == 1) { g = g2; b = b2; m = m2; v = v2; al = a2; be = be2; }
    else { g = g3; b = b3; m = m3; v = v3; al = a3; be = be3; }
    float a = g[e] / sqrtf(v[e] + 1e-5f);
    al[e] = a;
    be[e] = b[e] - m[e] * a;
  }
}

// ---------------- i8 MFMA layer: C = A x W^T ------------------------------
// Block 256(m) x 128(n) x BK=64 bytes, double-buffered LDS 2x24KB.
// 8 waves as 4(m) x 2(n); wave tile 64x64 = 4x4 mfma 16x16x64 tiles.
// LDS rows of 64B; 16B-chunk slot XOR-swizzled by (row&3) at global source.
// FINAL: dot with sign(wout) rows, atomicAdd exact-int partials into out.
template <int K, bool FINAL>
__global__ __launch_bounds__(512, 6) void layer_mfma(
    const char* __restrict__ A, const char* __restrict__ W,
    const float* __restrict__ alpha, const float* __restrict__ beta,
    char* __restrict__ O, const float* __restrict__ wout,
    float* __restrict__ out) {
  constexpr int N = Hid;
  constexpr int S = K / 64;
  __shared__ __align__(16) char lds[2][24576];  // per buf: A 16KB | B 8KB

  const int tid = threadIdx.x;
  const int wave = tid >> 6, lane = tid & 63;

  // XCD swizzle: xcd = id&7 owns m-panels [xcd*8, xcd*8+8)
  const int id = blockIdx.x;
  const int mp = (id & 7) * 8 + ((id >> 3) & 7);
  const int np = id >> 6;
  const int m0 = mp * 256, n0 = np * 128;

  // staging: 24 chunks of 1KB (A: cc 0..15 = 256 rows x 64B, B: 16..23)
  const char* gp[3];
  int loff[3];
#pragma unroll
  for (int ci = 0; ci < 3; ++ci) {
    int c = wave * 3 + ci;
    bool isA = c < 16;
    int cc = isA ? c : c - 16;
    int row = cc * 16 + (lane >> 2);
    int kc = (lane & 3) ^ (row & 3);  // logical k-chunk at this phys slot
    gp[ci] = (isA ? A + (size_t)(m0 + row) * K
                  : W + (size_t)(n0 + row) * K) + kc * 16;
    loff[ci] = (isA ? 0 : 16384) + cc * 1024;
  }

  const int lr = lane & 15, lk = lane >> 4;
  const int wm = wave >> 1, wn = wave & 1;
  const int aofs = (wm * 64 + lr) * 64 + (lk ^ (lr & 3)) * 16;
  const int bofs = 16384 + (wn * 64 + lr) * 64 + (lk ^ (lr & 3)) * 16;

  i32x4 acc[4][4] = {};

  // prologue: stage 0 into buf 0
#pragma unroll
  for (int ci = 0; ci < 3; ++ci) {
    ld16(gp[ci], &lds[0][loff[ci]]);
    gp[ci] += 64;
  }
  __syncthreads();

  int buf = 0;
  for (int ks = 0; ks < S; ++ks) {
    if (ks + 1 < S) {
#pragma unroll
      for (int ci = 0; ci < 3; ++ci) {
        ld16(gp[ci], &lds[buf ^ 1][loff[ci]]);
        gp[ci] += 64;
      }
    }
    const char* lb = &lds[buf][0];
    i32x4 aF[4], bF[4];
#pragma unroll
    for (int t = 0; t < 4; ++t) {
      aF[t] = *(const i32x4*)(lb + aofs + t * 1024);
      bF[t] = *(const i32x4*)(lb + bofs + t * 1024);
    }
#pragma unroll
    for (int mt = 0; mt < 4; ++mt)
#pragma unroll
      for (int nt = 0; nt < 4; ++nt)
        acc[mt][nt] = __builtin_amdgcn_mfma_i32_16x16x64_i8(
            aF[mt], bF[nt], acc[mt][nt], 0, 0, 0);
    __syncthreads();  // next-stage DMA drained + buf reuse protected
    buf ^= 1;
  }

  float al[4], be[4];
#pragma unroll
  for (int nt = 0; nt < 4; ++nt) {
    int n = n0 + wn * 64 + nt * 16 + lr;
    al[nt] = alpha[n];
    be[nt] = beta[n];
  }

  if (!FINAL) {
#pragma unroll
    for (int mt = 0; mt < 4; ++mt)
#pragma unroll
      for (int r = 0; r < 4; ++r) {
        int m = m0 + wm * 64 + mt * 16 + lk * 4 + r;  // C/D row=(lane>>4)*4+reg
        char* orow = O + (size_t)m * N;
#pragma unroll
        for (int nt = 0; nt < 4; ++nt) {
          float c = (float)acc[mt][nt][r];
          orow[n0 + wn * 64 + nt * 16 + lr] =
              (fmaf(al[nt], c, be[nt]) >= 0.0f) ? 1 : -1;
        }
      }
  } else {
    int ws0[4], ws1[4];
#pragma unroll
    for (int nt = 0; nt < 4; ++nt) {
      int n = n0 + wn * 64 + nt * 16 + lr;
      ws0[nt] = (wout[n] >= 0.0f) ? 1 : -1;
      ws1[nt] = (wout[2048 + n] >= 0.0f) ? 1 : -1;
    }
#pragma unroll
    for (int mt = 0; mt < 4; ++mt)
#pragma unroll
      for (int r = 0; r < 4; ++r) {
        int m = m0 + wm * 64 + mt * 16 + lk * 4 + r;
        int p0 = 0, p1 = 0;
#pragma unroll
        for (int nt = 0; nt < 4; ++nt) {
          float c = (float)acc[mt][nt][r];
          int a = (fmaf(al[nt], c, be[nt]) >= 0.0f) ? 1 : -1;
          p0 += a * ws0[nt];
          p1 += a * ws1[nt];
        }
#pragma unroll
        for (int off = 1; off <= 8; off <<= 1) {
          p0 += __shfl_xor(p0, off, 64);
          p1 += __shfl_xor(p1, off, 64);
        }
        if (lr == 0) {
          atomicAdd(&out[m * 2 + 0], (float)p0);
          atomicAdd(&out[m * 2 + 1], (float)p1);
        }
      }
  }
}

extern "C" void kernel_launch(void* const* d_in, const int* in_sizes, int n_in,
                              void* d_out, int out_size, void* d_ws, size_t ws_size,
                              hipStream_t stream) {
  const float* x    = (const float*)d_in[0];
  const float* w1   = (const float*)d_in[1];
  const float* g1   = (const float*)d_in[2];
  const float* b1   = (const float*)d_in[3];
  const float* m1   = (const float*)d_in[4];
  const float* v1   = (const float*)d_in[5];
  const float* w2   = (const float*)d_in[6];
  const float* g2   = (const float*)d_in[7];
  const float* b2   = (const float*)d_in[8];
  const float* m2   = (const float*)d_in[9];
  const float* v2   = (const float*)d_in[10];
  const float* w3   = (const float*)d_in[11];
  const float* g3   = (const float*)d_in[12];
  const float* b3   = (const float*)d_in[13];
  const float* m3   = (const float*)d_in[14];
  const float* v3   = (const float*)d_in[15];
  const float* wout = (const float*)d_in[16];
  float* out = (float*)d_out;

  char* base = (char*)d_ws;
  size_t off = 0;
  auto take = [&](size_t bytes) -> char* {
    char* p = base + off;
    off += (bytes + 255) & ~(size_t)255;
    return p;
  };
  char* A0  = take((size_t)Bsz * Din);
  char* Aa  = take((size_t)Bsz * Hid);
  char* Ab  = take((size_t)Bsz * Hid);
  char* W1s = take((size_t)Hid * Din);
  char* W2s = take((size_t)Hid * Hid);
  char* W3s = take((size_t)Hid * Hid);
  float* a1  = (float*)take(Hid * 4);
  float* be1 = (float*)take(Hid * 4);
  float* a2  = (float*)take(Hid * 4);
  float* be2 = (float*)take(Hid * 4);
  float* a3  = (float*)take(Hid * 4);
  float* be3 = (float*)take(Hid * 4);

  hipMemsetAsync(d_out, 0, (size_t)out_size * sizeof(float), stream);

  prep_kernel<<<26648, 256, 0, stream>>>(
      x, w1, w2, w3,
      g1, b1, m1, v1, g2, b2, m2, v2, g3, b3, m3, v3,
      A0, W1s, W2s, W3s, a1, be1, a2, be2, a3, be3);

  // grid 1024: (16384/256) m-panels x (2048/128) n-panels, XCD-swizzled
  layer_mfma<Din, false><<<1024, 512, 0, stream>>>(A0, W1s, a1, be1, Aa,
                                                   nullptr, nullptr);
  layer_mfma<Hid, false><<<1024, 512, 0, stream>>>(Aa, W2s, a2, be2, Ab,
                                                   nullptr, nullptr);
  layer_mfma<Hid, true><<<1024, 512, 0, stream>>>(Ab, W3s, a3, be3, nullptr,
                                                  wout, out);
}

// Round 6
// 353.187 us; speedup vs baseline: 3.0141x; 3.0141x over previous
//
#include <hip/hip_runtime.h>
#include <cstdint>
#include <cmath>

// Binarized MLP via i8 MFMA: 16384x1024 -> 2048 -> 2048 -> 2048 -> 2.
// Acts/weights are exactly {-1,+1} as i8; mfma_i32_16x16x64_i8 gives exact
// i32 accumulation. BN+binq folds to per-neuron float threshold.
// R6: 256x256 block (1024 thr, 16 waves 4x4, wave 64x64), BK=64,
// double-buffered 2x32KB LDS, __launch_bounds__(1024,4) so acc(64 AGPR)+
// frags+addr fit the 128-reg budget WITHOUT spilling (R5 post-mortem:
// (512,6) -> 85-reg cap -> acc spill -> 1.5GB scratch traffic).
// LDS 64B rows, 16B slot = kc ^ ((row>>1)&3): <=2-way bank alias (free).
// XCD swizzle keeps FETCH at ~compulsory; prep fused; final layer fused
// into layer-3 epilogue via exact-integer f32 atomics.

typedef int i32x4 __attribute__((ext_vector_type(4)));

static constexpr int Bsz = 16384;
static constexpr int Din = 1024;
static constexpr int Hid = 2048;

__device__ __forceinline__ void ld16(const void* g, void* l) {
  __builtin_amdgcn_global_load_lds(
      (const __attribute__((address_space(1))) void*)g,
      (__attribute__((address_space(3))) void*)l, 16, 0, 0);
}

// ---------------- fused prep: all sign-quantizations + BN folds ------------
__global__ void prep_kernel(
    const float* __restrict__ x, const float* __restrict__ w1,
    const float* __restrict__ w2, const float* __restrict__ w3,
    const float* __restrict__ g1, const float* __restrict__ b1,
    const float* __restrict__ m1, const float* __restrict__ v1,
    const float* __restrict__ g2, const float* __restrict__ b2,
    const float* __restrict__ m2, const float* __restrict__ v2,
    const float* __restrict__ g3, const float* __restrict__ b3,
    const float* __restrict__ m3, const float* __restrict__ v3,
    char* __restrict__ A0, char* __restrict__ W1s,
    char* __restrict__ W2s, char* __restrict__ W3s,
    float* __restrict__ a1, float* __restrict__ be1,
    float* __restrict__ a2, float* __restrict__ be2,
    float* __restrict__ a3, float* __restrict__ be3) {
  constexpr int BX = 16384, BW1 = 2048, BW2 = 4096, BW3 = 4096;
  const int blk = blockIdx.x;
  if (blk < BX + BW1 + BW2 + BW3) {
    const float* s;
    char* d;
    float thr = 0.0f;
    int rb;
    if (blk < BX) {
      s = x; d = A0; thr = 0.5f; rb = 0;
    } else if (blk < BX + BW1) {
      s = w1; d = W1s; rb = BX;
    } else if (blk < BX + BW1 + BW2) {
      s = w2; d = W2s; rb = BX + BW1;
    } else {
      s = w3; d = W3s; rb = BX + BW1 + BW2;
    }
    int i = (blk - rb) * 256 + threadIdx.x;
    float4 v = ((const float4*)s)[i];
    char4 o;
    o.x = (v.x >= thr) ? 1 : -1;
    o.y = (v.y >= thr) ? 1 : -1;
    o.z = (v.z >= thr) ? 1 : -1;
    o.w = (v.w >= thr) ? 1 : -1;
    ((char4*)d)[i] = o;
  } else {
    int t = (blk - (BX + BW1 + BW2 + BW3)) * 256 + threadIdx.x;  // 0..6143
    int l = t >> 11, e = t & 2047;
    const float *g, *b, *m, *v;
    float *al, *be;
    if (l == 0) { g = g1; b = b1; m = m1; v = v1; al = a1; be = be1; }
    else if (l == 1) { g = g2; b = b2; m = m2; v = v2; al = a2; be = be2; }
    else { g = g3; b = b3; m = m3; v = v3; al = a3; be = be3; }
    float a = g[e] / sqrtf(v[e] + 1e-5f);
    al[e] = a;
    be[e] = b[e] - m[e] * a;
  }
}

// ---------------- i8 MFMA layer: C = A x W^T ------------------------------
// Block 256(m) x 256(n) x BK=64 bytes, double-buffered LDS 2x32KB.
// 16 waves as 4(m) x 4(n); wave tile 64x64 = 4x4 mfma 16x16x64 tiles.
// LDS rows 64B; 16B slot holds logical chunk kc = slot ^ ((row>>1)&3).
template <int K, bool FINAL>
__global__ __launch_bounds__(1024, 4) void layer_mfma(
    const char* __restrict__ A, const char* __restrict__ W,
    const float* __restrict__ alpha, const float* __restrict__ beta,
    char* __restrict__ O, const float* __restrict__ wout,
    float* __restrict__ out) {
  constexpr int N = Hid;
  constexpr int S = K / 64;
  __shared__ __align__(16) char lds[2][32768];  // per buf: A 16KB | B 16KB

  const int tid = threadIdx.x;
  const int wave = tid >> 6, lane = tid & 63;

  // XCD swizzle: xcd = id&7 owns m-panels [xcd*8, xcd*8+8)
  const int id = blockIdx.x;                 // 512 blocks: 64 mp x 8 np
  const int t = id >> 3;
  const int mp = (id & 7) * 8 + (t & 7);
  const int np = t >> 3;
  const int m0 = mp * 256, n0 = np * 256;

  // staging: 32 chunks of 1KB/stage; wave w -> chunks 2w, 2w+1
  const char* gp[2];
  int loff[2];
#pragma unroll
  for (int ci = 0; ci < 2; ++ci) {
    int c = wave * 2 + ci;                   // 0..15 A, 16..31 B
    bool isA = c < 16;
    int cc = c & 15;
    int row = cc * 16 + (lane >> 2);         // local row 0..255
    int kc = (lane & 3) ^ ((row >> 1) & 3);  // logical chunk at phys slot
    gp[ci] = (isA ? A + (size_t)(m0 + row) * K
                  : W + (size_t)(n0 + row) * K) + kc * 16;
    loff[ci] = (isA ? 0 : 16384) + cc * 1024;
  }

  const int lr = lane & 15, lk = lane >> 4;
  const int wm = wave >> 2, wn = wave & 3;
  const int aofs = (wm * 64 + lr) * 64 + (lk ^ ((lr >> 1) & 3)) * 16;
  const int bofs = 16384 + (wn * 64 + lr) * 64 + (lk ^ ((lr >> 1) & 3)) * 16;

  i32x4 acc[4][4] = {};

  // prologue: stage 0 into buf 0
#pragma unroll
  for (int ci = 0; ci < 2; ++ci) {
    ld16(gp[ci], &lds[0][loff[ci]]);
    gp[ci] += 64;
  }
  __syncthreads();

  int buf = 0;
  for (int ks = 0; ks < S; ++ks) {
    if (ks + 1 < S) {
#pragma unroll
      for (int ci = 0; ci < 2; ++ci) {
        ld16(gp[ci], &lds[buf ^ 1][loff[ci]]);
        gp[ci] += 64;
      }
    }
    const char* lb = &lds[buf][0];
    i32x4 aF[4], bF[4];
#pragma unroll
    for (int tt = 0; tt < 4; ++tt) {
      aF[tt] = *(const i32x4*)(lb + aofs + tt * 1024);
      bF[tt] = *(const i32x4*)(lb + bofs + tt * 1024);
    }
#pragma unroll
    for (int mt = 0; mt < 4; ++mt)
#pragma unroll
      for (int nt = 0; nt < 4; ++nt)
        acc[mt][nt] = __builtin_amdgcn_mfma_i32_16x16x64_i8(
            aF[mt], bF[nt], acc[mt][nt], 0, 0, 0);
    __syncthreads();  // next-stage DMA drained + buf reuse protected
    buf ^= 1;
  }

  float al[4], be[4];
#pragma unroll
  for (int nt = 0; nt < 4; ++nt) {
    int n = n0 + wn * 64 + nt * 16 + lr;
    al[nt] = alpha[n];
    be[nt] = beta[n];
  }

  if (!FINAL) {
#pragma unroll
    for (int mt = 0; mt < 4; ++mt)
#pragma unroll
      for (int r = 0; r < 4; ++r) {
        int m = m0 + wm * 64 + mt * 16 + lk * 4 + r;  // C/D row=(lane>>4)*4+reg
        char* orow = O + (size_t)m * N;
#pragma unroll
        for (int nt = 0; nt < 4; ++nt) {
          float c = (float)acc[mt][nt][r];
          orow[n0 + wn * 64 + nt * 16 + lr] =
              (fmaf(al[nt], c, be[nt]) >= 0.0f) ? 1 : -1;
        }
      }
  } else {
    int ws0[4], ws1[4];
#pragma unroll
    for (int nt = 0; nt < 4; ++nt) {
      int n = n0 + wn * 64 + nt * 16 + lr;
      ws0[nt] = (wout[n] >= 0.0f) ? 1 : -1;
      ws1[nt] = (wout[2048 + n] >= 0.0f) ? 1 : -1;
    }
#pragma unroll
    for (int mt = 0; mt < 4; ++mt)
#pragma unroll
      for (int r = 0; r < 4; ++r) {
        int m = m0 + wm * 64 + mt * 16 + lk * 4 + r;
        int p0 = 0, p1 = 0;
#pragma unroll
        for (int nt = 0; nt < 4; ++nt) {
          float c = (float)acc[mt][nt][r];
          int a = (fmaf(al[nt], c, be[nt]) >= 0.0f) ? 1 : -1;
          p0 += a * ws0[nt];
          p1 += a * ws1[nt];
        }
#pragma unroll
        for (int off = 1; off <= 8; off <<= 1) {
          p0 += __shfl_xor(p0, off, 64);
          p1 += __shfl_xor(p1, off, 64);
        }
        if (lr == 0) {
          atomicAdd(&out[m * 2 + 0], (float)p0);
          atomicAdd(&out[m * 2 + 1], (float)p1);
        }
      }
  }
}

extern "C" void kernel_launch(void* const* d_in, const int* in_sizes, int n_in,
                              void* d_out, int out_size, void* d_ws, size_t ws_size,
                              hipStream_t stream) {
  const float* x    = (const float*)d_in[0];
  const float* w1   = (const float*)d_in[1];
  const float* g1   = (const float*)d_in[2];
  const float* b1   = (const float*)d_in[3];
  const float* m1   = (const float*)d_in[4];
  const float* v1   = (const float*)d_in[5];
  const float* w2   = (const float*)d_in[6];
  const float* g2   = (const float*)d_in[7];
  const float* b2   = (const float*)d_in[8];
  const float* m2   = (const float*)d_in[9];
  const float* v2   = (const float*)d_in[10];
  const float* w3   = (const float*)d_in[11];
  const float* g3   = (const float*)d_in[12];
  const float* b3   = (const float*)d_in[13];
  const float* m3   = (const float*)d_in[14];
  const float* v3   = (const float*)d_in[15];
  const float* wout = (const float*)d_in[16];
  float* out = (float*)d_out;

  char* base = (char*)d_ws;
  size_t off = 0;
  auto take = [&](size_t bytes) -> char* {
    char* p = base + off;
    off += (bytes + 255) & ~(size_t)255;
    return p;
  };
  char* A0  = take((size_t)Bsz * Din);
  char* Aa  = take((size_t)Bsz * Hid);
  char* Ab  = take((size_t)Bsz * Hid);
  char* W1s = take((size_t)Hid * Din);
  char* W2s = take((size_t)Hid * Hid);
  char* W3s = take((size_t)Hid * Hid);
  float* a1  = (float*)take(Hid * 4);
  float* be1 = (float*)take(Hid * 4);
  float* a2  = (float*)take(Hid * 4);
  float* be2 = (float*)take(Hid * 4);
  float* a3  = (float*)take(Hid * 4);
  float* be3 = (float*)take(Hid * 4);

  hipMemsetAsync(d_out, 0, (size_t)out_size * sizeof(float), stream);

  prep_kernel<<<26648, 256, 0, stream>>>(
      x, w1, w2, w3,
      g1, b1, m1, v1, g2, b2, m2, v2, g3, b3, m3, v3,
      A0, W1s, W2s, W3s, a1, be1, a2, be2, a3, be3);

  // grid 512: 64 m-panels x 8 n-panels (256x256 tiles), XCD-swizzled
  layer_mfma<Din, false><<<512, 1024, 0, stream>>>(A0, W1s, a1, be1, Aa,
                                                   nullptr, nullptr);
  layer_mfma<Hid, false><<<512, 1024, 0, stream>>>(Aa, W2s, a2, be2, Ab,
                                                   nullptr, nullptr);
  layer_mfma<Hid, true><<<512, 1024, 0, stream>>>(Ab, W3s, a3, be3, nullptr,
                                                  wout, out);
}

// Round 7
// 336.237 us; speedup vs baseline: 3.1660x; 1.0504x over previous
//
#include <hip/hip_runtime.h>
#include <cstdint>
#include <cmath>

// Binarized MLP via i8 MFMA: 16384x1024 -> 2048 -> 2048 -> 2048 -> 2.
// Acts/weights are exactly {-1,+1} as i8; mfma_i32_16x16x64_i8 gives exact
// i32 accumulation. BN+binq folds to per-neuron float threshold.
// R7: best-measured layer config (R3: 128x128 tile, BK=128, double-buffered
// 2x32KB LDS, 256 thr / 4 waves 2x2, wave 64x64) + XCD swizzle (R4/R6:
// np-inner so each XCD keeps W (4MB) L2-resident; FETCH ~compulsory).
// Prep fused (quant + bnprep + out-zeroing: no memset dispatch). Final
// 2-neuron layer fused into layer-3 epilogue; LDS pre-reduce across wn
// waves halves the atomic count.

typedef int i32x4 __attribute__((ext_vector_type(4)));

static constexpr int Bsz = 16384;
static constexpr int Din = 1024;
static constexpr int Hid = 2048;

__device__ __forceinline__ void ld16(const void* g, void* l) {
  __builtin_amdgcn_global_load_lds(
      (const __attribute__((address_space(1))) void*)g,
      (__attribute__((address_space(3))) void*)l, 16, 0, 0);
}

// ---------------- fused prep: quant + BN folds + out zeroing ---------------
__global__ void prep_kernel(
    const float* __restrict__ x, const float* __restrict__ w1,
    const float* __restrict__ w2, const float* __restrict__ w3,
    const float* __restrict__ g1, const float* __restrict__ b1,
    const float* __restrict__ m1, const float* __restrict__ v1,
    const float* __restrict__ g2, const float* __restrict__ b2,
    const float* __restrict__ m2, const float* __restrict__ v2,
    const float* __restrict__ g3, const float* __restrict__ b3,
    const float* __restrict__ m3, const float* __restrict__ v3,
    char* __restrict__ A0, char* __restrict__ W1s,
    char* __restrict__ W2s, char* __restrict__ W3s,
    float* __restrict__ a1, float* __restrict__ be1,
    float* __restrict__ a2, float* __restrict__ be2,
    float* __restrict__ a3, float* __restrict__ be3,
    float* __restrict__ out) {
  constexpr int BX = 16384, BW1 = 2048, BW2 = 4096, BW3 = 4096;
  constexpr int BQ = BX + BW1 + BW2 + BW3;      // 26624
  constexpr int BBN = 24;                        // 6144 bn threads
  const int blk = blockIdx.x;
  if (blk < BQ) {
    const float* s;
    char* d;
    float thr = 0.0f;
    int rb;
    if (blk < BX) {
      s = x; d = A0; thr = 0.5f; rb = 0;        // binq(2x-1)>=0 <=> x>=0.5
    } else if (blk < BX + BW1) {
      s = w1; d = W1s; rb = BX;
    } else if (blk < BX + BW1 + BW2) {
      s = w2; d = W2s; rb = BX + BW1;
    } else {
      s = w3; d = W3s; rb = BX + BW1 + BW2;
    }
    int i = (blk - rb) * 256 + threadIdx.x;
    float4 v = ((const float4*)s)[i];
    char4 o;
    o.x = (v.x >= thr) ? 1 : -1;
    o.y = (v.y >= thr) ? 1 : -1;
    o.z = (v.z >= thr) ? 1 : -1;
    o.w = (v.w >= thr) ? 1 : -1;
    ((char4*)d)[i] = o;
  } else if (blk < BQ + BBN) {
    int t = (blk - BQ) * 256 + threadIdx.x;     // 0..6143
    int l = t >> 11, e = t & 2047;
    const float *g, *b, *m, *v;
    float *al, *be;
    if (l == 0) { g = g1; b = b1; m = m1; v = v1; al = a1; be = be1; }
    else if (l == 1) { g = g2; b = b2; m = m2; v = v2; al = a2; be = be2; }
    else { g = g3; b = b3; m = m3; v = v3; al = a3; be = be3; }
    float a = g[e] / sqrtf(v[e] + 1e-5f);
    al[e] = a;
    be[e] = b[e] - m[e] * a;
  } else {
    int i = (blk - (BQ + BBN)) * 256 + threadIdx.x;  // 0..32767
    out[i] = 0.0f;
  }
}

// ---------------- i8 MFMA layer: C = A x W^T ------------------------------
// Block 128(m) x 128(n) x BK=128 bytes, double-buffered LDS 2x32KB.
// 4 waves as 2(m) x 2(n); wave tile 64x64 = 4x4 mfma 16x16x64 tiles.
// LDS rows of 128B; 16B slot XOR-swizzled by (row&7) at global source.
// XCD swizzle: xcd=id&7 owns mp range [xcd*16,xcd*16+16), np inner-fast
// so the full W (4MB) stays resident in each XCD's L2.
template <int K, bool FINAL>
__global__ __launch_bounds__(256, 2) void layer_mfma(
    const char* __restrict__ A, const char* __restrict__ W,
    const float* __restrict__ alpha, const float* __restrict__ beta,
    char* __restrict__ O, const float* __restrict__ wout,
    float* __restrict__ out) {
  constexpr int N = Hid;
  constexpr int S = K / 128;
  __shared__ __align__(16) char lds[2][32768];  // per buf: A 16KB | B 16KB

  const int tid = threadIdx.x;
  const int wave = tid >> 6, lane = tid & 63;

  const int id = blockIdx.x;                 // 2048 = 8 xcd * 16 mp * 16 np
  const int s_ = id >> 3;
  const int np = s_ & 15;                    // np fastest within XCD
  const int mp = (id & 7) * 16 + (s_ >> 4);
  const int m0 = mp * 128, n0 = np * 128;

  // staging: 32 chunks of 1KB (A cc 0..15 = 128 rows x 128B, B cc 0..15)
  const char* gp[8];
  int loff[8];
#pragma unroll
  for (int ci = 0; ci < 8; ++ci) {
    int c = wave * 8 + ci;                   // 0..15 A, 16..31 B
    bool isA = c < 16;
    int cc = c & 15;
    int row = cc * 8 + (lane >> 3);          // local row 0..127
    int kc = (lane & 7) ^ (row & 7);         // logical k-chunk at phys slot
    gp[ci] = (isA ? A + (size_t)(m0 + row) * K
                  : W + (size_t)(n0 + row) * K) + kc * 16;
    loff[ci] = (isA ? 0 : 16384) + cc * 1024;
  }

  const int lr = lane & 15, lk = lane >> 4;
  const int wm = wave >> 1, wn = wave & 1;
  int aofs[2], bofs[2];
#pragma unroll
  for (int s = 0; s < 2; ++s) {
    aofs[s] = (wm * 64 + lr) * 128 + ((s * 4 + lk) ^ (lr & 7)) * 16;
    bofs[s] = 16384 + (wn * 64 + lr) * 128 + ((s * 4 + lk) ^ (lr & 7)) * 16;
  }

  i32x4 acc[4][4] = {};

  // prologue: stage 0 into buf 0
#pragma unroll
  for (int ci = 0; ci < 8; ++ci) {
    ld16(gp[ci], &lds[0][loff[ci]]);
    gp[ci] += 128;
  }
  __syncthreads();

  int buf = 0;
  for (int ks = 0; ks < S; ++ks) {
    if (ks + 1 < S) {
#pragma unroll
      for (int ci = 0; ci < 8; ++ci) {
        ld16(gp[ci], &lds[buf ^ 1][loff[ci]]);
        gp[ci] += 128;
      }
    }
    const char* lb = &lds[buf][0];
#pragma unroll
    for (int s = 0; s < 2; ++s) {
      i32x4 aF[4], bF[4];
#pragma unroll
      for (int t = 0; t < 4; ++t) {
        aF[t] = *(const i32x4*)(lb + aofs[s] + t * 2048);
        bF[t] = *(const i32x4*)(lb + bofs[s] + t * 2048);
      }
#pragma unroll
      for (int mt = 0; mt < 4; ++mt)
#pragma unroll
        for (int nt = 0; nt < 4; ++nt)
          acc[mt][nt] = __builtin_amdgcn_mfma_i32_16x16x64_i8(
              aF[mt], bF[nt], acc[mt][nt], 0, 0, 0);
    }
    __syncthreads();  // next-stage DMA drained + buf reuse protected
    buf ^= 1;
  }

  float al[4], be[4];
#pragma unroll
  for (int nt = 0; nt < 4; ++nt) {
    int n = n0 + wn * 64 + nt * 16 + lr;
    al[nt] = alpha[n];
    be[nt] = beta[n];
  }

  if (!FINAL) {
#pragma unroll
    for (int mt = 0; mt < 4; ++mt)
#pragma unroll
      for (int r = 0; r < 4; ++r) {
        int m = m0 + wm * 64 + mt * 16 + lk * 4 + r;  // C/D row=(lane>>4)*4+reg
        char* orow = O + (size_t)m * N;
#pragma unroll
        for (int nt = 0; nt < 4; ++nt) {
          float c = (float)acc[mt][nt][r];
          orow[n0 + wn * 64 + nt * 16 + lr] =
              (fmaf(al[nt], c, be[nt]) >= 0.0f) ? 1 : -1;
        }
      }
  } else {
    int ws0[4], ws1[4];
#pragma unroll
    for (int nt = 0; nt < 4; ++nt) {
      int n = n0 + wn * 64 + nt * 16 + lr;
      ws0[nt] = (wout[n] >= 0.0f) ? 1 : -1;
      ws1[nt] = (wout[2048 + n] >= 0.0f) ? 1 : -1;
    }
    int2* red = (int2*)&lds[0][0];  // [128 rows][2 wn] partial (p0,p1)
#pragma unroll
    for (int mt = 0; mt < 4; ++mt)
#pragma unroll
      for (int r = 0; r < 4; ++r) {
        int p0 = 0, p1 = 0;
#pragma unroll
        for (int nt = 0; nt < 4; ++nt) {
          float c = (float)acc[mt][nt][r];
          int a = (fmaf(al[nt], c, be[nt]) >= 0.0f) ? 1 : -1;
          p0 += a * ws0[nt];
          p1 += a * ws1[nt];
        }
#pragma unroll
        for (int off = 1; off <= 8; off <<= 1) {
          p0 += __shfl_xor(p0, off, 64);
          p1 += __shfl_xor(p1, off, 64);
        }
        if (lr == 0) {
          int idx = wm * 64 + mt * 16 + lk * 4 + r;   // 0..127
          red[idx * 2 + wn] = make_int2(p0, p1);
        }
      }
    __syncthreads();
    if (tid < 128) {
      int2 a = red[tid * 2 + 0], b = red[tid * 2 + 1];
      atomicAdd(&out[(m0 + tid) * 2 + 0], (float)(a.x + b.x));
      atomicAdd(&out[(m0 + tid) * 2 + 1], (float)(a.y + b.y));
    }
  }
}

extern "C" void kernel_launch(void* const* d_in, const int* in_sizes, int n_in,
                              void* d_out, int out_size, void* d_ws, size_t ws_size,
                              hipStream_t stream) {
  const float* x    = (const float*)d_in[0];
  const float* w1   = (const float*)d_in[1];
  const float* g1   = (const float*)d_in[2];
  const float* b1   = (const float*)d_in[3];
  const float* m1   = (const float*)d_in[4];
  const float* v1   = (const float*)d_in[5];
  const float* w2   = (const float*)d_in[6];
  const float* g2   = (const float*)d_in[7];
  const float* b2   = (const float*)d_in[8];
  const float* m2   = (const float*)d_in[9];
  const float* v2   = (const float*)d_in[10];
  const float* w3   = (const float*)d_in[11];
  const float* g3   = (const float*)d_in[12];
  const float* b3   = (const float*)d_in[13];
  const float* m3   = (const float*)d_in[14];
  const float* v3   = (const float*)d_in[15];
  const float* wout = (const float*)d_in[16];
  float* out = (float*)d_out;

  char* base = (char*)d_ws;
  size_t off = 0;
  auto take = [&](size_t bytes) -> char* {
    char* p = base + off;
    off += (bytes + 255) & ~(size_t)255;
    return p;
  };
  char* A0  = take((size_t)Bsz * Din);
  char* Aa  = take((size_t)Bsz * Hid);
  char* Ab  = take((size_t)Bsz * Hid);
  char* W1s = take((size_t)Hid * Din);
  char* W2s = take((size_t)Hid * Hid);
  char* W3s = take((size_t)Hid * Hid);
  float* a1  = (float*)take(Hid * 4);
  float* be1 = (float*)take(Hid * 4);
  float* a2  = (float*)take(Hid * 4);
  float* be2 = (float*)take(Hid * 4);
  float* a3  = (float*)take(Hid * 4);
  float* be3 = (float*)take(Hid * 4);

  // prep: 26624 quant blocks + 24 bnprep blocks + 128 out-zero blocks
  prep_kernel<<<26776, 256, 0, stream>>>(
      x, w1, w2, w3,
      g1, b1, m1, v1, g2, b2, m2, v2, g3, b3, m3, v3,
      A0, W1s, W2s, W3s, a1, be1, a2, be2, a3, be3, out);

  // grid 2048: 8 xcd x 16 mp x 16 np (128x128 tiles)
  layer_mfma<Din, false><<<2048, 256, 0, stream>>>(A0, W1s, a1, be1, Aa,
                                                   nullptr, nullptr);
  layer_mfma<Hid, false><<<2048, 256, 0, stream>>>(Aa, W2s, a2, be2, Ab,
                                                   nullptr, nullptr);
  layer_mfma<Hid, true><<<2048, 256, 0, stream>>>(Ab, W3s, a3, be3, nullptr,
                                                  wout, out);
}